// Round 6
// baseline (150.415 us; speedup 1.0000x reference)
//
#include <hip/hip_runtime.h>

typedef short bf16x8 __attribute__((ext_vector_type(8)));
typedef float f32x4 __attribute__((ext_vector_type(4)));

#define D 128
#define NROW 98304          // 3 groups * 64 mc * 512 rows
#define NPANEL (NROW / 16)  // 6144 16-row panels, 4 KB each
#define X_BYTES ((size_t)NPANEL * 4096)
#define INV_COUNT 5.9604644775390625e-08f   // 1 / (64*512*512)

__device__ __forceinline__ unsigned short f2bf(float f) {
    unsigned u = __float_as_uint(f);
    u += 0x7FFFu + ((u >> 16) & 1u);        // round-to-nearest-even
    return (unsigned short)(u >> 16);
}
__device__ __forceinline__ float bf2f(unsigned short h) {
    return __uint_as_float(((unsigned)h) << 16);
}

// One block = one 16-row panel. X is stored MFMA-panel-major:
//   byte(panel p, granule g, row r) = p*4096 + g*256 + r*16
// so a 16x16x32 A/B fragment load in dist is base + lane*16 (1 KB contiguous).
// Thread t: r = t&15, g = t>>4; computes granule g of row r (8 bf16).
// Store address = panel_base + t*16 -> perfectly coalesced.
__global__ __launch_bounds__(256) void prep_kernel(
    const float* __restrict__ mu, const float* __restrict__ sigma,
    const float* __restrict__ epsA, const float* __restrict__ epsB,
    const float* __restrict__ epsC,
    unsigned short* __restrict__ Xp, float* __restrict__ sumsq,
    float* __restrict__ out)
{
    if (blockIdx.x == 0 && threadIdx.x == 0) out[0] = 0.f;
    const int p = blockIdx.x;              // panel
    const int t = threadIdx.x;
    const int r = t & 15, g = t >> 4;      // row-in-panel, granule
    const int R = p * 16 + r;              // global row
    const int n  = R & 511;
    const int gm = R >> 9;                 // gslice*64 + m
    const int gs = gm >> 6;
    const int m  = gm & 63;
    const float* eps = (gs == 0) ? epsA : (gs == 1) ? epsB : epsC;
    const float* erow = eps   + ((size_t)m * 512 + n) * D;
    const float* urow = mu    + ((size_t)(gs * 512 + n)) * D;
    const float* srow = sigma + ((size_t)(gs * 512 + n)) * D;
    float4 e0 = ((const float4*)erow)[g * 2], e1 = ((const float4*)erow)[g * 2 + 1];
    float4 u0 = ((const float4*)urow)[g * 2], u1 = ((const float4*)urow)[g * 2 + 1];
    float4 s0 = ((const float4*)srow)[g * 2], s1 = ((const float4*)srow)[g * 2 + 1];

    unsigned short b0 = f2bf(fmaf(s0.x, e0.x, u0.x));
    unsigned short b1 = f2bf(fmaf(s0.y, e0.y, u0.y));
    unsigned short b2 = f2bf(fmaf(s0.z, e0.z, u0.z));
    unsigned short b3 = f2bf(fmaf(s0.w, e0.w, u0.w));
    unsigned short b4 = f2bf(fmaf(s1.x, e1.x, u1.x));
    unsigned short b5 = f2bf(fmaf(s1.y, e1.y, u1.y));
    unsigned short b6 = f2bf(fmaf(s1.z, e1.z, u1.z));
    unsigned short b7 = f2bf(fmaf(s1.w, e1.w, u1.w));

    uint4 pk;
    pk.x = (unsigned)b0 | ((unsigned)b1 << 16);
    pk.y = (unsigned)b2 | ((unsigned)b3 << 16);
    pk.z = (unsigned)b4 | ((unsigned)b5 << 16);
    pk.w = (unsigned)b6 | ((unsigned)b7 << 16);
    *(uint4*)((char*)Xp + (size_t)p * 4096 + t * 16) = pk;

    float f0 = bf2f(b0), f1 = bf2f(b1), f2 = bf2f(b2), f3 = bf2f(b3);
    float f4 = bf2f(b4), f5 = bf2f(b5), f6 = bf2f(b6), f7 = bf2f(b7);
    float ss = f0*f0 + f1*f1 + f2*f2 + f3*f3 + f4*f4 + f5*f5 + f6*f6 + f7*f7;
    // reduce over g (16 chunks) for each r: lanes {r, r+16, r+32, r+48} per wave,
    // then across the 4 waves via tiny LDS.
    ss += __shfl_down(ss, 32, 64);
    ss += __shfl_down(ss, 16, 64);
    __shared__ float part[4][16];
    const int wave = t >> 6, lane = t & 63;
    if (lane < 16) part[wave][lane] = ss;
    __syncthreads();
    if (t < 16) sumsq[p * 16 + t] = part[0][t] + part[1][t] + part[2][t] + part[3][t];
}

// One block = one 128x128 tile. NO LDS staging, NO barriers in the main path:
// panel-major layout makes every fragment load a contiguous 1 KB
// global_load_dwordx4 (uniform base + lane*16), served from L2 via the
// XCD-aware slice mapping. Compiler pipelines loads across K freely.
__global__ __launch_bounds__(256, 3) void dist_kernel(
    const unsigned short* __restrict__ Xp, const float* __restrict__ sumsq,
    float* __restrict__ out)
{
    const int bx   = blockIdx.x;          // 0..3071
    const int xcd  = bx & 7;
    const int k    = bx >> 3;             // 0..383
    const int j    = k >> 4;              // 0..23
    const int tile = k & 15;
    const int s    = xcd + 8 * j;         // slice 0..191 = dist*64 + m
    const int dist = s >> 6;
    const int m    = s & 63;
    const int tn   = tile >> 2, tk = tile & 3;

    // dist 0: AC (x=A=0, y=C=2); dist 1: BA (x=B=1, y=A=0); dist 2: BC (x=B=1, y=C=2)
    const int gx = (dist == 0) ? 0 : 1;
    const int gy = (dist == 1) ? 0 : 2;

    // panel base: global row block (slice*512 + tn*128) -> panel index /16
    const char* Ab = (const char*)Xp + ((size_t)((gx * 64 + m) * 32 + tn * 8)) * 4096;
    const char* Bb = (const char*)Xp + ((size_t)((gy * 64 + m) * 32 + tk * 8)) * 4096;
    const float* ssx = sumsq + ((size_t)(gx * 64 + m)) * 512 + tn * 128;
    const float* ssy = sumsq + ((size_t)(gy * 64 + m)) * 512 + tk * 128;

    const int t = threadIdx.x;
    const int wave = t >> 6, lane = t & 63;
    const int wr = (wave >> 1) * 64, wc = (wave & 1) * 64;
    const int l15 = lane & 15, quad = lane >> 4;

    // wave's quadrant: +4 panels per 64 rows; lane*16 covers (granule,row)
    const char* Aw = Ab + (wave >> 1) * 16384 + lane * 16;
    const char* Bw = Bb + (wave & 1) * 16384 + lane * 16;

    f32x4 acc[4][4] = {};
    #pragma unroll
    for (int ks = 0; ks < 4; ks++) {
        bf16x8 a[4], b[4];
        #pragma unroll
        for (int fr = 0; fr < 4; fr++)
            a[fr] = *(const bf16x8*)(Aw + fr * 4096 + ks * 1024);
        #pragma unroll
        for (int fc = 0; fc < 4; fc++)
            b[fc] = *(const bf16x8*)(Bw + fc * 4096 + ks * 1024);
        #pragma unroll
        for (int fr = 0; fr < 4; fr++)
            #pragma unroll
            for (int fc = 0; fc < 4; fc++)
                acc[fr][fc] = __builtin_amdgcn_mfma_f32_16x16x32_bf16(
                    a[fr], b[fc], acc[fr][fc], 0, 0, 0);
    }

    // epilogue: d2 = x2 + y2 - 2*dot; C layout: col=lane&15, row=quad*4+i
    float lsum = 0.f;
    #pragma unroll
    for (int fc = 0; fc < 4; fc++) {
        float y2 = ssy[wc + fc * 16 + l15];
        #pragma unroll
        for (int fr = 0; fr < 4; fr++) {
            #pragma unroll
            for (int i = 0; i < 4; i++) {
                float x2 = ssx[wr + fr * 16 + quad * 4 + i];
                float d2 = fmaxf(fmaf(-2.f, acc[fr][fc][i], x2 + y2), 1e-12f);
                if (dist == 0) {
                    lsum += d2;                               // mean(dAC^2)
                } else if (d2 < 4.f) {                        // relu(M - d), M=2
                    float td = 2.f - sqrtf(d2);
                    lsum += td * td;
                }
            }
        }
    }

    #pragma unroll
    for (int o = 32; o > 0; o >>= 1) lsum += __shfl_down(lsum, o, 64);
    __shared__ float red[4];
    if (lane == 0) red[wave] = lsum;
    __syncthreads();
    if (t == 0) {
        atomicAdd(out, (red[0] + red[1] + red[2] + red[3]) * INV_COUNT);
    }
}

extern "C" void kernel_launch(void* const* d_in, const int* in_sizes, int n_in,
                              void* d_out, int out_size, void* d_ws, size_t ws_size,
                              hipStream_t stream) {
    const float* mu    = (const float*)d_in[0];
    const float* sigma = (const float*)d_in[1];
    const float* epsA  = (const float*)d_in[2];
    const float* epsB  = (const float*)d_in[3];
    const float* epsC  = (const float*)d_in[4];
    float* out = (float*)d_out;

    unsigned short* Xp = (unsigned short*)d_ws;               // 25.17 MB panels
    float* sumsq = (float*)((char*)d_ws + X_BYTES);           // 0.39 MB

    prep_kernel<<<NPANEL, 256, 0, stream>>>(mu, sigma, epsA, epsB, epsC, Xp, sumsq, out);

    dist_kernel<<<3072, 256, 0, stream>>>(Xp, sumsq, out);
}

// Round 7
// 134.722 us; speedup vs baseline: 1.1165x; 1.1165x over previous
//
#include <hip/hip_runtime.h>

typedef short bf16x8 __attribute__((ext_vector_type(8)));
typedef float f32x4 __attribute__((ext_vector_type(4)));

#define D 128
#define NROW 98304          // 3 groups * 64 mc * 512 rows
#define X_ELEMS ((size_t)NROW * D)          // bf16 elements in ws
#define INV_COUNT 5.9604644775390625e-08f   // 1 / (64*512*512)

typedef __attribute__((address_space(3))) void  as3_void;
typedef const __attribute__((address_space(1))) void as1_cvoid;

__device__ __forceinline__ void gl2lds16(const void* g, void* l) {
    __builtin_amdgcn_global_load_lds((as1_cvoid*)g, (as3_void*)l, 16, 0, 0);
}
__device__ __forceinline__ void gl2lds4(const void* g, void* l) {
    __builtin_amdgcn_global_load_lds((as1_cvoid*)g, (as3_void*)l, 4, 0, 0);
}

__device__ __forceinline__ unsigned short f2bf(float f) {
    unsigned u = __float_as_uint(f);
    u += 0x7FFFu + ((u >> 16) & 1u);        // round-to-nearest-even
    return (unsigned short)(u >> 16);
}
__device__ __forceinline__ float bf2f(unsigned short h) {
    return __uint_as_float(((unsigned)h) << 16);
}

// 8 rows per block; 32 threads per row: float4 loads, 8B bf16 store,
// width-32 shuffle reduce for sum(x_bf16^2). Also zeroes the out accumulator.
__global__ __launch_bounds__(256) void prep_kernel(
    const float* __restrict__ mu, const float* __restrict__ sigma,
    const float* __restrict__ epsA, const float* __restrict__ epsB,
    const float* __restrict__ epsC,
    unsigned short* __restrict__ Xb, float* __restrict__ sumsq,
    float* __restrict__ out)
{
    if (blockIdx.x == 0 && threadIdx.x == 0) out[0] = 0.f;
    int t = threadIdx.x;
    int row  = blockIdx.x * 8 + (t >> 5);   // 0..NROW-1
    int ci   = t & 31;                      // float4 index within row
    int n  = row & 511;
    int gm = row >> 9;        // g*64 + m
    int g  = gm >> 6;
    int m  = gm & 63;
    const float* eps = (g == 0) ? epsA : (g == 1) ? epsB : epsC;
    float4 e = ((const float4*)(eps + ((size_t)m * 512 + n) * D))[ci];
    float4 u = ((const float4*)(mu    + ((size_t)(g * 512 + n)) * D))[ci];
    float4 s = ((const float4*)(sigma + ((size_t)(g * 512 + n)) * D))[ci];
    unsigned short b0 = f2bf(fmaf(s.x, e.x, u.x));
    unsigned short b1 = f2bf(fmaf(s.y, e.y, u.y));
    unsigned short b2 = f2bf(fmaf(s.z, e.z, u.z));
    unsigned short b3 = f2bf(fmaf(s.w, e.w, u.w));
    float f0 = bf2f(b0), f1 = bf2f(b1), f2 = bf2f(b2), f3 = bf2f(b3);
    float ss = f0 * f0 + f1 * f1 + f2 * f2 + f3 * f3;
    uint2 packed;
    packed.x = (unsigned)b0 | ((unsigned)b1 << 16);
    packed.y = (unsigned)b2 | ((unsigned)b3 << 16);
    ((uint2*)(Xb + (size_t)row * D))[ci] = packed;
    #pragma unroll
    for (int o = 16; o > 0; o >>= 1) ss += __shfl_down(ss, o, 32);
    if (ci == 0) sumsq[row] = ss;
}

// Strip-persistent dist, 512 threads (8 waves), 1 block/CU.
// Block = (slice, tn): 128x512 strip. As (32 KB) staged once; Bs full-K
// double-buffer 2x32 KB. Per phase: issue next Bs DMA FIRST, then compute a
// full K=128 tile (~700+ cyc) so the vmcnt(0)-at-barrier finds the DMA done.
__global__ __launch_bounds__(512, 2) void dist_kernel(
    const unsigned short* __restrict__ Xb, const float* __restrict__ sumsq,
    float* __restrict__ out)
{
    const int bx  = blockIdx.x;           // 0..767
    const int xcd = bx & 7;               // XCD round-robin -> slice locality
    const int q   = bx >> 3;              // 0..95
    const int j   = q >> 2;               // 0..23
    const int tn  = q & 3;
    const int s   = xcd + 8 * j;          // slice 0..191 = dist*64 + m
    const int dist = s >> 6;
    const int m    = s & 63;

    // dist 0: AC (x=A=0, y=C=2); dist 1: BA (x=B=1, y=A=0); dist 2: BC (x=B=1, y=C=2)
    const int gx = (dist == 0) ? 0 : 1;
    const int gy = (dist == 1) ? 0 : 2;

    const char* Xa = (const char*)(Xb + (((size_t)(gx * 64 + m)) * 512 + tn * 128) * D);
    const char* Xc = (const char*)(Xb + (((size_t)(gy * 64 + m)) * 512) * D);  // full slice
    const float* ssx = sumsq + ((size_t)(gx * 64 + m)) * 512 + tn * 128;
    const float* ssy = sumsq + ((size_t)(gy * 64 + m)) * 512;

    __shared__ unsigned short As[128 * 128];        // 32 KB, K-full A strip
    __shared__ unsigned short Bs[2][128 * 128];     // 2 x 32 KB K-full B tiles
    __shared__ float ss_s[640];                     // [0:128) x2 | [128:640) y2
    __shared__ float red[8];

    const int t = threadIdx.x;
    const int wave = t >> 6, lane = t & 63;
    const int wr = (wave >> 2) * 64;      // row quadrant (0 or 64)
    const int wc = (wave & 3) * 32;       // col strip (0/32/64/96)
    const int l15 = lane & 15, quad = lane >> 4;
    const int dr4 = lane >> 4, g16 = lane & 15;   // staging: 4 rows / instr

    // ---- fill: As (once), Bs[0] (tile 0), sumsq rows ----
    #pragma unroll
    for (int i = 0; i < 4; i++) {
        const int r0 = wave * 16 + i * 4;
        const int row = r0 + dr4;
        gl2lds16(Xa + row * 256 + ((g16 ^ (row & 7)) * 16), &As[r0 * 128]);
    }
    #pragma unroll
    for (int i = 0; i < 4; i++) {
        const int r0 = wave * 16 + i * 4;
        const int row = r0 + dr4;
        gl2lds16(Xc + row * 256 + ((g16 ^ (row & 7)) * 16), &Bs[0][r0 * 128]);
    }
    {
        const int idx = wave;             // 0..7
        const float* src = (idx < 2) ? (ssx + idx * 64) : (ssy + (idx - 2) * 64);
        gl2lds4(src + lane, &ss_s[idx * 64]);
        if (wave < 2) {                   // idx 8,9 -> ssy chunks 6,7
            const float* s2 = ssy + (wave + 6) * 64;
            gl2lds4(s2 + lane, &ss_s[(wave + 8) * 64]);
        }
    }
    __syncthreads();

    float lsum = 0.f;

    #pragma unroll
    for (int tk = 0; tk < 4; tk++) {
        const int buf = tk & 1;
        if (tk < 3) {                     // prefetch next tile's Bs into other buf
            #pragma unroll
            for (int i = 0; i < 4; i++) {
                const int r0 = wave * 16 + i * 4;
                const int row = r0 + dr4;
                gl2lds16(Xc + ((tk + 1) * 128 + row) * 256 + ((g16 ^ (row & 7)) * 16),
                         &Bs[buf ^ 1][r0 * 128]);
            }
        }
        // ---- compute tile tk: K=128 in 4 steps ----
        f32x4 acc[4][2] = {};
        #pragma unroll
        for (int ks = 0; ks < 4; ks++) {
            const int pa = ((ks * 4 + quad) ^ (l15 & 7)) * 8;   // swizzled granule
            bf16x8 a[4], b[2];
            #pragma unroll
            for (int fr = 0; fr < 4; fr++)
                a[fr] = *(bf16x8*)&As[(wr + fr * 16 + l15) * 128 + pa];
            #pragma unroll
            for (int fc = 0; fc < 2; fc++)
                b[fc] = *(bf16x8*)&Bs[buf][(wc + fc * 16 + l15) * 128 + pa];
            #pragma unroll
            for (int fr = 0; fr < 4; fr++)
                #pragma unroll
                for (int fc = 0; fc < 2; fc++)
                    acc[fr][fc] = __builtin_amdgcn_mfma_f32_16x16x32_bf16(
                        a[fr], b[fc], acc[fr][fc], 0, 0, 0);
        }
        // ---- epilogue: d2 = x2 + y2 - 2*dot; C layout: col=lane&15, row=quad*4+i
        #pragma unroll
        for (int fc = 0; fc < 2; fc++) {
            float y2 = ss_s[128 + tk * 128 + wc + fc * 16 + l15];
            #pragma unroll
            for (int fr = 0; fr < 4; fr++) {
                #pragma unroll
                for (int i = 0; i < 4; i++) {
                    float x2 = ss_s[wr + fr * 16 + quad * 4 + i];
                    float d2 = fmaxf(fmaf(-2.f, acc[fr][fc][i], x2 + y2), 1e-12f);
                    if (dist == 0) {
                        lsum += d2;                       // mean(dAC^2)
                    } else if (d2 < 4.f) {                // relu(M - d), M=2
                        float td = 2.f - sqrtf(d2);
                        lsum += td * td;
                    }
                }
            }
        }
        __syncthreads();
    }

    #pragma unroll
    for (int o = 32; o > 0; o >>= 1) lsum += __shfl_down(lsum, o, 64);
    if (lane == 0) red[wave] = lsum;
    __syncthreads();
    if (t == 0) {
        float bs = 0.f;
        #pragma unroll
        for (int w = 0; w < 8; w++) bs += red[w];
        atomicAdd(out, bs * INV_COUNT);
    }
}

extern "C" void kernel_launch(void* const* d_in, const int* in_sizes, int n_in,
                              void* d_out, int out_size, void* d_ws, size_t ws_size,
                              hipStream_t stream) {
    const float* mu    = (const float*)d_in[0];
    const float* sigma = (const float*)d_in[1];
    const float* epsA  = (const float*)d_in[2];
    const float* epsB  = (const float*)d_in[3];
    const float* epsC  = (const float*)d_in[4];
    float* out = (float*)d_out;

    unsigned short* Xb = (unsigned short*)d_ws;              // 25.17 MB bf16
    float* sumsq = (float*)((char*)d_ws + X_ELEMS * sizeof(unsigned short)); // 0.39 MB

    prep_kernel<<<NROW / 8, 256, 0, stream>>>(mu, sigma, epsA, epsB, epsC, Xb, sumsq, out);

    dist_kernel<<<768, 512, 0, stream>>>(Xb, sumsq, out);
}

// Round 8
// 131.489 us; speedup vs baseline: 1.1439x; 1.0246x over previous
//
#include <hip/hip_runtime.h>

typedef short bf16x8 __attribute__((ext_vector_type(8)));
typedef float f32x4 __attribute__((ext_vector_type(4)));

#define D 128
#define NROW 98304          // 3 groups * 64 mc * 512 rows
#define X_ELEMS ((size_t)NROW * D)          // bf16 elements in ws
#define NBLK 3072                           // dist blocks = partial slots
#define INV_COUNT 5.9604644775390625e-08f   // 1 / (64*512*512)

typedef __attribute__((address_space(3))) void  as3_void;
typedef const __attribute__((address_space(1))) void as1_cvoid;

__device__ __forceinline__ void gl2lds16(const void* g, void* l) {
    __builtin_amdgcn_global_load_lds((as1_cvoid*)g, (as3_void*)l, 16, 0, 0);
}
__device__ __forceinline__ void gl2lds4(const void* g, void* l) {
    __builtin_amdgcn_global_load_lds((as1_cvoid*)g, (as3_void*)l, 4, 0, 0);
}

__device__ __forceinline__ unsigned short f2bf(float f) {
    unsigned u = __float_as_uint(f);
    u += 0x7FFFu + ((u >> 16) & 1u);        // round-to-nearest-even
    return (unsigned short)(u >> 16);
}
__device__ __forceinline__ float bf2f(unsigned short h) {
    return __uint_as_float(((unsigned)h) << 16);
}

// 8 rows per block; 32 threads per row: float4 loads, 8B bf16 store,
// width-32 shuffle reduce for sum(x_bf16^2).
__global__ __launch_bounds__(256) void prep_kernel(
    const float* __restrict__ mu, const float* __restrict__ sigma,
    const float* __restrict__ epsA, const float* __restrict__ epsB,
    const float* __restrict__ epsC,
    unsigned short* __restrict__ Xb, float* __restrict__ sumsq)
{
    int t = threadIdx.x;
    int row  = blockIdx.x * 8 + (t >> 5);   // 0..NROW-1
    int ci   = t & 31;                      // float4 index within row
    int n  = row & 511;
    int gm = row >> 9;        // g*64 + m
    int g  = gm >> 6;
    int m  = gm & 63;
    const float* eps = (g == 0) ? epsA : (g == 1) ? epsB : epsC;
    float4 e = ((const float4*)(eps + ((size_t)m * 512 + n) * D))[ci];
    float4 u = ((const float4*)(mu    + ((size_t)(g * 512 + n)) * D))[ci];
    float4 s = ((const float4*)(sigma + ((size_t)(g * 512 + n)) * D))[ci];
    unsigned short b0 = f2bf(fmaf(s.x, e.x, u.x));
    unsigned short b1 = f2bf(fmaf(s.y, e.y, u.y));
    unsigned short b2 = f2bf(fmaf(s.z, e.z, u.z));
    unsigned short b3 = f2bf(fmaf(s.w, e.w, u.w));
    float f0 = bf2f(b0), f1 = bf2f(b1), f2 = bf2f(b2), f3 = bf2f(b3);
    float ss = f0 * f0 + f1 * f1 + f2 * f2 + f3 * f3;
    uint2 packed;
    packed.x = (unsigned)b0 | ((unsigned)b1 << 16);
    packed.y = (unsigned)b2 | ((unsigned)b3 << 16);
    ((uint2*)(Xb + (size_t)row * D))[ci] = packed;
    #pragma unroll
    for (int o = 16; o > 0; o >>= 1) ss += __shfl_down(ss, o, 32);
    if (ci == 0) sumsq[row] = ss;
}

// One block = one 128x128 tile of one distance matrix for one mc sample.
// Single-shot global_load_lds staging (R4 structure: best profiled), XCD-aware
// slice mapping for L2 residency. Partial sum -> plain store to pslots[bx]
// (NO atomics: 3072 same-line device-scope atomicAdds cost a ~30-45 us
// serialized tail at the coherence point -- the R1-R7 wall-invariance).
__global__ __launch_bounds__(256, 2) void dist_kernel(
    const unsigned short* __restrict__ Xb, const float* __restrict__ sumsq,
    float* __restrict__ pslots)
{
    const int bx   = blockIdx.x;          // 0..3071
    const int xcd  = bx & 7;
    const int k    = bx >> 3;             // 0..383
    const int j    = k >> 4;              // 0..23
    const int tile = k & 15;
    const int s    = xcd + 8 * j;         // slice 0..191 = dist*64 + m
    const int dist = s >> 6;
    const int m    = s & 63;
    const int tn   = tile >> 2, tk = tile & 3;

    // dist 0: AC (x=A=0, y=C=2); dist 1: BA (x=B=1, y=A=0); dist 2: BC (x=B=1, y=C=2)
    const int gx = (dist == 0) ? 0 : 1;
    const int gy = (dist == 1) ? 0 : 2;

    const char* Xa = (const char*)(Xb + (((size_t)(gx * 64 + m)) * 512 + tn * 128) * D);
    const char* Xc = (const char*)(Xb + (((size_t)(gy * 64 + m)) * 512 + tk * 128) * D);
    const float* ssx = sumsq + ((size_t)(gx * 64 + m)) * 512 + tn * 128;
    const float* ssy = sumsq + ((size_t)(gy * 64 + m)) * 512 + tk * 128;

    __shared__ unsigned short lds[2 * 128 * 128];   // 64 KB
    __shared__ float ss_s[256];                     // x2 rows | y2 rows
    unsigned short* As = lds;
    unsigned short* Bs = lds + 128 * 128;

    const int t = threadIdx.x;
    const int wave = t >> 6, lane = t & 63;
    const int wr = (wave >> 1) * 64;      // wave's 64x64 quadrant
    const int wc = (wave & 1) * 64;
    const int l15 = lane & 15, quad = lane >> 4;

    // ---- staging: LDS granule c = row*16 + (g ^ (row&7)); lane covers LDS
    // granules in order, so the XOR goes into the global gather address.
    {
        const int dr = lane >> 4;          // row within the 4-row instr span
        const int sg = lane & 15;          // LDS granule within row
        const int voffE = dr * 256 + ((sg ^ dr) * 16);        // r0%8 == 0
        const int voffO = dr * 256 + ((sg ^ (dr + 4)) * 16);  // r0%8 == 4
        #pragma unroll
        for (int i = 0; i < 8; i++) {
            const int r0 = wave * 32 + i * 4;
            const int voff = (i & 1) ? voffO : voffE;
            gl2lds16(Xa + r0 * 256 + voff, &As[r0 * 128]);
            gl2lds16(Xc + r0 * 256 + voff, &Bs[r0 * 128]);
        }
        const float* sp = (wave & 2) ? ssy : ssx;
        gl2lds4(sp + (wave & 1) * 64 + lane, &ss_s[wave * 64]);
    }
    __syncthreads();

    // ---- MFMA main: K=128 in 4 steps of 32 ----
    f32x4 acc[4][4] = {};
    #pragma unroll
    for (int ks = 0; ks < 4; ks++) {
        const int gsw = ((ks * 4 + quad) ^ (l15 & 7)) * 8;   // swizzled granule, shorts
        bf16x8 a[4], b[4];
        #pragma unroll
        for (int fr = 0; fr < 4; fr++)
            a[fr] = *(bf16x8*)&As[(wr + fr * 16 + l15) * 128 + gsw];
        #pragma unroll
        for (int fc = 0; fc < 4; fc++)
            b[fc] = *(bf16x8*)&Bs[(wc + fc * 16 + l15) * 128 + gsw];
        #pragma unroll
        for (int fr = 0; fr < 4; fr++)
            #pragma unroll
            for (int fc = 0; fc < 4; fc++)
                acc[fr][fc] = __builtin_amdgcn_mfma_f32_16x16x32_bf16(
                    a[fr], b[fc], acc[fr][fc], 0, 0, 0);
    }

    // ---- epilogue: d2 = x2 + y2 - 2*dot; C layout: col=lane&15, row=quad*4+i
    float lsum = 0.f;
    #pragma unroll
    for (int fc = 0; fc < 4; fc++) {
        float y2 = ss_s[128 + wc + fc * 16 + l15];
        #pragma unroll
        for (int fr = 0; fr < 4; fr++) {
            #pragma unroll
            for (int i = 0; i < 4; i++) {
                float x2 = ss_s[wr + fr * 16 + quad * 4 + i];
                float d2 = fmaxf(fmaf(-2.f, acc[fr][fc][i], x2 + y2), 1e-12f);
                if (dist == 0) {
                    lsum += d2;                               // mean(dAC^2)
                } else if (d2 < 4.f) {                        // relu(M - d), M=2
                    float td = 2.f - sqrtf(d2);
                    lsum += td * td;
                }
            }
        }
    }

    #pragma unroll
    for (int o = 32; o > 0; o >>= 1) lsum += __shfl_down(lsum, o, 64);
    __syncthreads();                      // ss_s reads done; safe to reuse
    float* red = ss_s;
    if (lane == 0) red[wave] = lsum;
    __syncthreads();
    if (t == 0)
        pslots[bx] = red[0] + red[1] + red[2] + red[3];   // plain store, no atomic
}

// Final reduction: 1 block, 256 threads, 12 floats each -> out[0].
__global__ __launch_bounds__(256) void reduce_kernel(
    const float* __restrict__ pslots, float* __restrict__ out)
{
    const int t = threadIdx.x;
    float s = 0.f;
    #pragma unroll
    for (int i = 0; i < 3; i++) {
        float4 v = ((const float4*)pslots)[t + i * 256];
        s += v.x + v.y + v.z + v.w;
    }
    #pragma unroll
    for (int o = 32; o > 0; o >>= 1) s += __shfl_down(s, o, 64);
    __shared__ float red[4];
    const int wave = t >> 6, lane = t & 63;
    if (lane == 0) red[wave] = s;
    __syncthreads();
    if (t == 0) out[0] = (red[0] + red[1] + red[2] + red[3]) * INV_COUNT;
}

extern "C" void kernel_launch(void* const* d_in, const int* in_sizes, int n_in,
                              void* d_out, int out_size, void* d_ws, size_t ws_size,
                              hipStream_t stream) {
    const float* mu    = (const float*)d_in[0];
    const float* sigma = (const float*)d_in[1];
    const float* epsA  = (const float*)d_in[2];
    const float* epsB  = (const float*)d_in[3];
    const float* epsC  = (const float*)d_in[4];
    float* out = (float*)d_out;

    unsigned short* Xb = (unsigned short*)d_ws;              // 25.17 MB bf16
    float* sumsq  = (float*)((char*)d_ws + X_ELEMS * sizeof(unsigned short)); // 0.39 MB
    float* pslots = sumsq + NROW;                            // 12 KB partials

    prep_kernel<<<NROW / 8, 256, 0, stream>>>(mu, sigma, epsA, epsB, epsC, Xb, sumsq);

    dist_kernel<<<NBLK, 256, 0, stream>>>(Xb, sumsq, pslots);

    reduce_kernel<<<1, 256, 0, stream>>>(pslots, out);
}

// Round 9
// 117.083 us; speedup vs baseline: 1.2847x; 1.1230x over previous
//
#include <hip/hip_runtime.h>

typedef short bf16x8 __attribute__((ext_vector_type(8)));
typedef float f32x4 __attribute__((ext_vector_type(4)));

#define D 128
#define NROW 98304          // 3 groups * 64 mc * 512 rows
#define X_ELEMS ((size_t)NROW * D)          // bf16 elements in ws
#define NBLK 3072                           // dist blocks = partial slots
#define INV_COUNT 5.9604644775390625e-08f   // 1 / (64*512*512)

typedef __attribute__((address_space(3))) void  as3_void;
typedef const __attribute__((address_space(1))) void as1_cvoid;

__device__ __forceinline__ void gl2lds16(const void* g, void* l) {
    __builtin_amdgcn_global_load_lds((as1_cvoid*)g, (as3_void*)l, 16, 0, 0);
}
__device__ __forceinline__ void gl2lds4(const void* g, void* l) {
    __builtin_amdgcn_global_load_lds((as1_cvoid*)g, (as3_void*)l, 4, 0, 0);
}

__device__ __forceinline__ unsigned short f2bf(float f) {
    unsigned u = __float_as_uint(f);
    u += 0x7FFFu + ((u >> 16) & 1u);        // round-to-nearest-even
    return (unsigned short)(u >> 16);
}
__device__ __forceinline__ float bf2f(unsigned short h) {
    return __uint_as_float(((unsigned)h) << 16);
}

// 8 rows per block; 32 threads per row: float4 loads, 8B bf16 store,
// width-32 shuffle reduce for sum(x_bf16^2).
__global__ __launch_bounds__(256) void prep_kernel(
    const float* __restrict__ mu, const float* __restrict__ sigma,
    const float* __restrict__ epsA, const float* __restrict__ epsB,
    const float* __restrict__ epsC,
    unsigned short* __restrict__ Xb, float* __restrict__ sumsq)
{
    int t = threadIdx.x;
    int row  = blockIdx.x * 8 + (t >> 5);   // 0..NROW-1
    int ci   = t & 31;                      // float4 index within row
    int n  = row & 511;
    int gm = row >> 9;        // g*64 + m
    int g  = gm >> 6;
    int m  = gm & 63;
    const float* eps = (g == 0) ? epsA : (g == 1) ? epsB : epsC;
    float4 e = ((const float4*)(eps + ((size_t)m * 512 + n) * D))[ci];
    float4 u = ((const float4*)(mu    + ((size_t)(g * 512 + n)) * D))[ci];
    float4 s = ((const float4*)(sigma + ((size_t)(g * 512 + n)) * D))[ci];
    unsigned short b0 = f2bf(fmaf(s.x, e.x, u.x));
    unsigned short b1 = f2bf(fmaf(s.y, e.y, u.y));
    unsigned short b2 = f2bf(fmaf(s.z, e.z, u.z));
    unsigned short b3 = f2bf(fmaf(s.w, e.w, u.w));
    float f0 = bf2f(b0), f1 = bf2f(b1), f2 = bf2f(b2), f3 = bf2f(b3);
    float ss = f0 * f0 + f1 * f1 + f2 * f2 + f3 * f3;
    uint2 packed;
    packed.x = (unsigned)b0 | ((unsigned)b1 << 16);
    packed.y = (unsigned)b2 | ((unsigned)b3 << 16);
    ((uint2*)(Xb + (size_t)row * D))[ci] = packed;
    #pragma unroll
    for (int o = 16; o > 0; o >>= 1) ss += __shfl_down(ss, o, 32);
    if (ci == 0) sumsq[row] = ss;
}

// One block = one 128x128 tile. K=128 split into two 32 KB stage+compute
// phases through ONE half-K LDS buffer -> 32.25 KB -> 4 blocks/CU. Every
// barrier drain is covered by 3 other resident blocks. Staging is
// global_load_lds DMA from the XCD-local L2 (slice swizzle).
__global__ __launch_bounds__(256, 4) void dist_kernel(
    const unsigned short* __restrict__ Xb, const float* __restrict__ sumsq,
    float* __restrict__ pslots)
{
    const int bx   = blockIdx.x;          // 0..3071
    const int xcd  = bx & 7;
    const int k    = bx >> 3;             // 0..383
    const int j    = k >> 4;              // 0..23
    const int tile = k & 15;
    const int s    = xcd + 8 * j;         // slice 0..191 = dist*64 + m
    const int dist = s >> 6;
    const int m    = s & 63;
    const int tn   = tile >> 2, tk = tile & 3;

    // dist 0: AC (x=A=0, y=C=2); dist 1: BA (x=B=1, y=A=0); dist 2: BC (x=B=1, y=C=2)
    const int gx = (dist == 0) ? 0 : 1;
    const int gy = (dist == 1) ? 0 : 2;

    const char* Xa = (const char*)(Xb + (((size_t)(gx * 64 + m)) * 512 + tn * 128) * D);
    const char* Xc = (const char*)(Xb + (((size_t)(gy * 64 + m)) * 512 + tk * 128) * D);
    const float* ssx = sumsq + ((size_t)(gx * 64 + m)) * 512 + tn * 128;
    const float* ssy = sumsq + ((size_t)(gy * 64 + m)) * 512 + tk * 128;

    __shared__ unsigned short As[128 * 64];   // 16 KB, half-K A
    __shared__ unsigned short Bs[128 * 64];   // 16 KB, half-K B
    __shared__ float ss_s[256];               // x2 rows | y2 rows

    const int t = threadIdx.x;
    const int wave = t >> 6, lane = t & 63;
    const int wr = (wave >> 1) * 64;      // wave's 64x64 quadrant
    const int wc = (wave & 1) * 64;
    const int l15 = lane & 15, quad = lane >> 4;

    // staging lane map: 8 rows x 8 granules per instr (1 KB). Row half = 128 B.
    // LDS granule-in-row sg = lane&7; global granule g = sg ^ (row&7), row&7 = dr8.
    const int dr8 = lane >> 3, g8 = lane & 7;
    const int voff = dr8 * 256 + ((g8 ^ dr8) * 16);

    f32x4 acc[4][4] = {};

    // ---- phase 0: stage K-cols [0,64) + ss rows ----
    #pragma unroll
    for (int i = 0; i < 4; i++) {
        const int r0 = wave * 32 + i * 8;
        gl2lds16(Xa + r0 * 256 + voff, &As[r0 * 64]);
        gl2lds16(Xc + r0 * 256 + voff, &Bs[r0 * 64]);
    }
    {
        const float* sp = (wave & 2) ? ssy : ssx;
        gl2lds4(sp + (wave & 1) * 64 + lane, &ss_s[wave * 64]);
    }
    __syncthreads();

    #pragma unroll
    for (int ks = 0; ks < 2; ks++) {
        const int base = ((ks * 4 + quad) ^ (l15 & 7)) * 8;
        bf16x8 a[4], b[4];
        #pragma unroll
        for (int fr = 0; fr < 4; fr++)
            a[fr] = *(bf16x8*)&As[(wr + fr * 16 + l15) * 64 + base];
        #pragma unroll
        for (int fc = 0; fc < 4; fc++)
            b[fc] = *(bf16x8*)&Bs[(wc + fc * 16 + l15) * 64 + base];
        #pragma unroll
        for (int fr = 0; fr < 4; fr++)
            #pragma unroll
            for (int fc = 0; fc < 4; fc++)
                acc[fr][fc] = __builtin_amdgcn_mfma_f32_16x16x32_bf16(
                    a[fr], b[fc], acc[fr][fc], 0, 0, 0);
    }
    __syncthreads();

    // ---- phase 1: stage K-cols [64,128) into the same buffer ----
    #pragma unroll
    for (int i = 0; i < 4; i++) {
        const int r0 = wave * 32 + i * 8;
        gl2lds16(Xa + r0 * 256 + 128 + voff, &As[r0 * 64]);
        gl2lds16(Xc + r0 * 256 + 128 + voff, &Bs[r0 * 64]);
    }
    __syncthreads();

    #pragma unroll
    for (int ks = 0; ks < 2; ks++) {
        const int base = ((ks * 4 + quad) ^ (l15 & 7)) * 8;
        bf16x8 a[4], b[4];
        #pragma unroll
        for (int fr = 0; fr < 4; fr++)
            a[fr] = *(bf16x8*)&As[(wr + fr * 16 + l15) * 64 + base];
        #pragma unroll
        for (int fc = 0; fc < 4; fc++)
            b[fc] = *(bf16x8*)&Bs[(wc + fc * 16 + l15) * 64 + base];
        #pragma unroll
        for (int fr = 0; fr < 4; fr++)
            #pragma unroll
            for (int fc = 0; fc < 4; fc++)
                acc[fr][fc] = __builtin_amdgcn_mfma_f32_16x16x32_bf16(
                    a[fr], b[fc], acc[fr][fc], 0, 0, 0);
    }

    // ---- epilogue: d2 = x2 + y2 - 2*dot; C layout: col=lane&15, row=quad*4+i
    float lsum = 0.f;
    #pragma unroll
    for (int fc = 0; fc < 4; fc++) {
        float y2 = ss_s[128 + wc + fc * 16 + l15];
        #pragma unroll
        for (int fr = 0; fr < 4; fr++) {
            #pragma unroll
            for (int i = 0; i < 4; i++) {
                float x2 = ss_s[wr + fr * 16 + quad * 4 + i];
                float d2 = fmaxf(fmaf(-2.f, acc[fr][fc][i], x2 + y2), 1e-12f);
                if (dist == 0) {
                    lsum += d2;                               // mean(dAC^2)
                } else if (d2 < 4.f) {                        // relu(M - d), M=2
                    float td = 2.f - sqrtf(d2);
                    lsum += td * td;
                }
            }
        }
    }

    #pragma unroll
    for (int o = 32; o > 0; o >>= 1) lsum += __shfl_down(lsum, o, 64);
    __syncthreads();                      // ss_s reads done; safe to reuse
    float* red = ss_s;
    if (lane == 0) red[wave] = lsum;
    __syncthreads();
    if (t == 0)
        pslots[bx] = red[0] + red[1] + red[2] + red[3];   // plain store, no atomic
}

// Final reduction: 1 block, 256 threads, 12 floats each -> out[0].
__global__ __launch_bounds__(256) void reduce_kernel(
    const float* __restrict__ pslots, float* __restrict__ out)
{
    const int t = threadIdx.x;
    float s = 0.f;
    #pragma unroll
    for (int i = 0; i < 3; i++) {
        float4 v = ((const float4*)pslots)[t + i * 256];
        s += v.x + v.y + v.z + v.w;
    }
    #pragma unroll
    for (int o = 32; o > 0; o >>= 1) s += __shfl_down(s, o, 64);
    __shared__ float red[4];
    const int wave = t >> 6, lane = t & 63;
    if (lane == 0) red[wave] = s;
    __syncthreads();
    if (t == 0) out[0] = (red[0] + red[1] + red[2] + red[3]) * INV_COUNT;
}

extern "C" void kernel_launch(void* const* d_in, const int* in_sizes, int n_in,
                              void* d_out, int out_size, void* d_ws, size_t ws_size,
                              hipStream_t stream) {
    const float* mu    = (const float*)d_in[0];
    const float* sigma = (const float*)d_in[1];
    const float* epsA  = (const float*)d_in[2];
    const float* epsB  = (const float*)d_in[3];
    const float* epsC  = (const float*)d_in[4];
    float* out = (float*)d_out;

    unsigned short* Xb = (unsigned short*)d_ws;              // 25.17 MB bf16
    float* sumsq  = (float*)((char*)d_ws + X_ELEMS * sizeof(unsigned short)); // 0.39 MB
    float* pslots = sumsq + NROW;                            // 12 KB partials

    prep_kernel<<<NROW / 8, 256, 0, stream>>>(mu, sigma, epsA, epsB, epsC, Xb, sumsq);

    dist_kernel<<<NBLK, 256, 0, stream>>>(Xb, sumsq, pslots);

    reduce_kernel<<<1, 256, 0, stream>>>(pslots, out);
}